// Round 1
// baseline (69.977 us; speedup 1.0000x reference)
//
#include <hip/hip_runtime.h>

// STFT -> ISTFT round-trip with matched pinv bases is algebraically the
// identity on the input (see analysis): mag/phase recombination reproduces
// re/im exactly; inv basis satisfies pinv(fb)@fb = I over the window; the
// overlap-add / window-sumsquare normalization cancels; the final crop
// removes the reflect pad. Output (32,1,160000) fp32 == input (32,160000).
//
// So the kernel is a pure D2D copy. Use a vectorized grid-stride copy
// kernel (float4) — equivalent to hipMemcpyAsync but keeps everything in
// one explicitly-controlled launch.

__global__ __launch_bounds__(256) void identity_copy_f4(
    const float4* __restrict__ src, float4* __restrict__ dst, int n4) {
    int i = blockIdx.x * blockDim.x + threadIdx.x;
    int stride = gridDim.x * blockDim.x;
    for (; i < n4; i += stride) {
        dst[i] = src[i];
    }
}

extern "C" void kernel_launch(void* const* d_in, const int* in_sizes, int n_in,
                              void* d_out, int out_size, void* d_ws, size_t ws_size,
                              hipStream_t stream) {
    const float* x = (const float*)d_in[0];
    float* out = (float*)d_out;

    // out_size == in_sizes[0] == 32*160000 == 5,120,000 (divisible by 4)
    int n4 = out_size / 4;
    int block = 256;
    // Enough blocks to saturate 256 CUs; grid-stride handles the rest.
    int grid = (n4 + block - 1) / block;
    if (grid > 8192) grid = 8192;

    identity_copy_f4<<<grid, block, 0, stream>>>(
        (const float4*)x, (float4*)out, n4);
}